// Round 20
// baseline (651.726 us; speedup 1.0000x reference)
//
#include <hip/hip_runtime.h>
#include <stdint.h>
#include <stddef.h>

#define TOK 8192
#define H 1024
#define IDIM 2048
#define NE 32
#define BM 128
#define BK 64
#define MAX_TILES 96

typedef __attribute__((ext_vector_type(8))) short short8;
typedef __attribute__((ext_vector_type(4))) float f32x4;
typedef __attribute__((ext_vector_type(4))) float float4v;
typedef __attribute__((ext_vector_type(4))) unsigned int uint4v;

// ---- helpers -------------------------------------------------------------

__device__ __forceinline__ unsigned short f2bf(float x) {   // RNE fp32->bf16
  unsigned u = __builtin_bit_cast(unsigned, x);
  u += 0x7fffu + ((u >> 16) & 1u);
  return (unsigned short)(u >> 16);
}

// HW packed convert: lo -> bits[15:0], hi -> bits[31:16], RNE.
__device__ __forceinline__ unsigned cvtpk(float lo, float hi) {
  unsigned r;
  asm("v_cvt_pk_bf16_f32 %0, %1, %2" : "=v"(r) : "v"(lo), "v"(hi));
  return r;
}

// async global->LDS, 16B per lane; LDS dest = wave-uniform base + lane*16
__device__ __forceinline__ void gll16(const void* g, void* l) {
  __builtin_amdgcn_global_load_lds(
      (const __attribute__((address_space(1))) unsigned int*)g,
      (__attribute__((address_space(3))) unsigned int*)l, 16, 0, 0);
}

__device__ __forceinline__ f32x4 mfma16(short8 a, short8 b, f32x4 c) {
  return __builtin_amdgcn_mfma_f32_16x16x32_bf16(a, b, c, 0, 0, 0);
}

// ---- 0) weight transpose+convert: [K][N] fp32 -> [N][K] bf16 -------------

__global__ __launch_bounds__(256) void tconv_kernel(
    const float* __restrict__ src0, unsigned short* __restrict__ dst0,
    int K, int N)
{
  __shared__ float t[64][65];
  const size_t mat = (size_t)K * N;
  const float* src = src0 + (size_t)blockIdx.z * mat;
  unsigned short* dst = dst0 + (size_t)blockIdx.z * mat;
  const int k0 = blockIdx.x * 64, n0 = blockIdx.y * 64;
  const int tid = threadIdx.x;
  {
    const int r = tid >> 4;
    const int c = (tid & 15) * 4;
    #pragma unroll
    for (int i = 0; i < 4; ++i) {
      float4v v = *(const float4v*)(src + (size_t)(k0 + r + i * 16) * N + (n0 + c));
      t[r + i * 16][c + 0] = v[0];
      t[r + i * 16][c + 1] = v[1];
      t[r + i * 16][c + 2] = v[2];
      t[r + i * 16][c + 3] = v[3];
    }
  }
  __syncthreads();
  {
    const int n = tid >> 2;
    const int kc = (tid & 3) * 16;
    uint4v o0, o1;
    #pragma unroll
    for (int q = 0; q < 4; ++q) {
      o0[q] = cvtpk(t[kc + 2 * q][n],     t[kc + 2 * q + 1][n]);
      o1[q] = cvtpk(t[kc + 8 + 2 * q][n], t[kc + 8 + 2 * q + 1][n]);
    }
    unsigned short* dp = dst + (size_t)(n0 + n) * K + (k0 + kc);
    *(uint4v*)dp = o0;
    *(uint4v*)(dp + 8) = o1;
  }
}

// ---- 1) router: logits, top-1, sigmoid, bf16 casts ----------------------

__global__ __launch_bounds__(256) void router_kernel(
    const float* __restrict__ x, const float* __restrict__ gw,
    unsigned short* __restrict__ xbf, unsigned short* __restrict__ xsbf,
    int* __restrict__ expert_id, int* __restrict__ counts)
{
  __shared__ float xl[8 * H];          // 8 token rows, 32KB
  __shared__ float plog[8][8][NE];     // [chunk][tok][e]
  __shared__ float sscore[8];
  const int tid = threadIdx.x;
  const long t0 = (long)blockIdx.x * 8;

  const float4v* src = (const float4v*)(x + t0 * H);
  float4v* dst = (float4v*)xl;
  #pragma unroll
  for (int i = 0; i < 8; ++i) dst[tid + i * 256] = src[tid + i * 256];
  __syncthreads();

  {
    const int e = tid & 31, c = tid >> 5;
    float acc[8] = {0, 0, 0, 0, 0, 0, 0, 0};
    const float* gp = gw + (c * 128) * NE + e;
    for (int h = 0; h < 128; ++h) {
      float g = gp[h * NE];
      const float* xr = xl + (c * 128 + h);
      #pragma unroll
      for (int tk = 0; tk < 8; ++tk) acc[tk] += xr[tk * H] * g;
    }
    #pragma unroll
    for (int tk = 0; tk < 8; ++tk) plog[c][tk][e] = acc[tk];
  }
  __syncthreads();
  {
    const int e = tid & 31, tok = tid >> 5;
    float lg = 0.f;
    #pragma unroll
    for (int c = 0; c < 8; ++c) lg += plog[c][tok][e];
    float m = lg; int be = e;
    #pragma unroll
    for (int mask = 16; mask >= 1; mask >>= 1) {   // reduce within 32-lane group
      float om = __shfl_xor(m, mask);
      int   oe = __shfl_xor(be, mask);
      if (om > m || (om == m && oe < be)) { m = om; be = oe; }  // first-index tie
    }
    if (e == 0) {
      sscore[tok] = 1.f / (1.f + __expf(-m));
      expert_id[t0 + tok] = be;
      atomicAdd(&counts[be], 1);
    }
  }
  __syncthreads();
  {
    const float sc = sscore[tid >> 5];
    const int base = (tid >> 5) * H + (tid & 31) * 32;
    #pragma unroll
    for (int i = 0; i < 4; ++i) {
      uint4v vx, vs;
      #pragma unroll
      for (int q = 0; q < 4; ++q) {
        const float a = xl[base + i * 8 + 2 * q];
        const float b = xl[base + i * 8 + 2 * q + 1];
        vx[q] = cvtpk(a, b);
        vs[q] = cvtpk(a * sc, b * sc);
      }
      *(uint4v*)(xbf  + t0 * H + base + i * 8) = vx;
      *(uint4v*)(xsbf + t0 * H + base + i * 8) = vs;
    }
  }
}

// ---- 2) scan: offsets, cursors, tile table ------------------------------

__global__ void scan_kernel(const int* __restrict__ counts, int* __restrict__ offsets,
                            int* __restrict__ cursor, int* __restrict__ tile_e,
                            int* __restrict__ tile_p, int* __restrict__ n_tiles)
{
  if (threadIdx.x != 0) return;
  int off = 0, nt = 0;
  for (int e = 0; e < NE; ++e) {
    offsets[e] = off; cursor[e] = off;
    int cc = counts[e];
    for (int k = 0; k < cc; k += BM) { tile_e[nt] = e; tile_p[nt] = off + k; ++nt; }
    off += cc;
  }
  offsets[NE] = off;
  n_tiles[0] = nt;
}

// ---- 3) perm build -------------------------------------------------------

__global__ __launch_bounds__(256) void perm_kernel(
    const int* __restrict__ expert_id, int* __restrict__ cursor, int* __restrict__ perm)
{
  int t = blockIdx.x * 256 + threadIdx.x;
  int e = expert_id[t];
  int pos = atomicAdd(&cursor[e], 1);
  perm[pos] = t;
}

// ---- 4) MERGED fused gate+up GEMM (shared + routed, r18-proven) ----------
// GRID SWAPPED (r19 post-mortem): blockIdx.x = n-panel (FAST), blockIdx.y =
// M-tile (slow). Consecutive blocks share the same A tile (L2-hot, read
// ~once/tile) while streaming different weight panels (read once anyway).
// r19 order re-read all 32MB of A from HBM once per n-panel (16x).

__global__ __launch_bounds__(256, 2) void gu_kernel(
    const unsigned short* __restrict__ xbf,
    const unsigned short* __restrict__ xsbf,
    const unsigned short* __restrict__ SG, const unsigned short* __restrict__ SU,
    const unsigned short* __restrict__ RG, const unsigned short* __restrict__ RU,
    unsigned short* __restrict__ act_sh, unsigned short* __restrict__ act_rt,
    const int* __restrict__ perm, const int* __restrict__ tile_e,
    const int* __restrict__ tile_p, const int* __restrict__ offsets,
    const int* __restrict__ n_tiles)
{
  __shared__ short Al[BM * BK];   // 16KB [row][k] swizzled byte^=(r&7)<<4
  __shared__ short Gl[128 * BK];  // 16KB [n][k] same swizzle
  __shared__ short Ul[128 * BK];  // 16KB  (48KB total)

  const int tid = threadIdx.x;
  const int wave = tid >> 6, lane = tid & 63;
  const int wm = wave >> 1, wn = wave & 1;

  const int bidx = blockIdx.y;            // M-tile (slow dim)
  const bool routed = bidx >= (TOK / BM);
  int row0, row_end;
  const unsigned short *Gt, *Ut, *A;
  unsigned short* act;
  if (routed) {
    const int tx = bidx - TOK / BM;
    if (tx >= *n_tiles) return;
    const int e = tile_e[tx];
    row0 = tile_p[tx];
    row_end = offsets[e + 1];
    Gt = RG + (size_t)e * H * IDIM;
    Ut = RU + (size_t)e * H * IDIM;
    A = xsbf; act = act_rt;
  } else {
    row0 = bidx * BM; row_end = row0 + BM;
    Gt = SG; Ut = SU;
    A = xbf; act = act_sh;
  }
  const int n0 = blockIdx.x * 128;        // n-panel (fast dim)

  // staging descriptors: wave w stages rows [32w,32w+32) of each tile
  const unsigned short *asrc[4], *gsrc[4], *usrc[4];
  int soff[4];
  #pragma unroll
  for (int i = 0; i < 4; ++i) {
    const int r = wave * 32 + i * 8 + (lane >> 3);
    int p = row0 + r;
    if (routed && p >= row_end) p = row0;
    const int arow = routed ? perm[p] : p;
    const int cb = ((lane & 7) * 16) ^ ((r & 7) << 4);
    asrc[i] = A  + (size_t)arow * H + (cb >> 1);
    gsrc[i] = Gt + (size_t)(n0 + r) * H + (cb >> 1);
    usrc[i] = Ut + (size_t)(n0 + r) * H + (cb >> 1);
    soff[i] = (wave * 32 + i * 8) * BK;
  }

  f32x4 accg[4][4] = {};
  f32x4 accu[4][4] = {};

  #pragma unroll 1
  for (int kt = 0; kt < H / BK; ++kt) {
    __syncthreads();                    // prev compute done
    #pragma unroll
    for (int i = 0; i < 4; ++i) gll16(asrc[i] + kt * BK, Al + soff[i]);
    #pragma unroll
    for (int i = 0; i < 4; ++i) gll16(gsrc[i] + kt * BK, Gl + soff[i]);
    #pragma unroll
    for (int i = 0; i < 4; ++i) gll16(usrc[i] + kt * BK, Ul + soff[i]);
    __syncthreads();                    // vmcnt drained, tiles visible

    #pragma unroll
    for (int kk = 0; kk < 2; ++kk) {
      short8 af[4];
      #pragma unroll
      for (int m = 0; m < 4; ++m) {
        const int r = wm * 64 + m * 16 + (lane & 15);
        const int cb = (kk * 64 + ((lane >> 4) * 16)) ^ ((r & 7) << 4);
        af[m] = *(const short8*)((const char*)Al + r * 128 + cb);
      }
      #pragma unroll
      for (int nf = 0; nf < 4; ++nf) {
        const int n = wn * 64 + nf * 16 + (lane & 15);
        const int cb = (kk * 64 + ((lane >> 4) * 16)) ^ ((n & 7) << 4);
        short8 bg = *(const short8*)((const char*)Gl + n * 128 + cb);
        short8 bu = *(const short8*)((const char*)Ul + n * 128 + cb);
        #pragma unroll
        for (int m = 0; m < 4; ++m) {
          accg[m][nf] = mfma16(af[m], bg, accg[m][nf]);
          accu[m][nf] = mfma16(af[m], bu, accu[m][nf]);
        }
      }
    }
  }

  // epilogue: silu(g)*u -> bf16 act
  #pragma unroll
  for (int m = 0; m < 4; ++m)
    #pragma unroll
    for (int nf = 0; nf < 4; ++nf) {
      const int col = n0 + wn * 64 + nf * 16 + (lane & 15);
      #pragma unroll
      for (int j = 0; j < 4; ++j) {
        const int row = row0 + wm * 64 + m * 16 + ((lane >> 4) * 4) + j;
        if (routed && row >= row_end) continue;
        const float g = accg[m][nf][j];
        const float u = accu[m][nf][j];
        const float v = (g / (1.f + __expf(-g))) * u;
        act[(size_t)row * IDIM + col] = f2bf(v);
      }
    }
}

// ---- 5) down GEMM (serial pair, grid swapped): out = act @ Wd ------------
// blockIdx.x = n-panel (fast), blockIdx.y = M-tile (slow) -> act tile L2-hot.

template<bool ROUTED>
__global__ __launch_bounds__(256, 4) void dn_kernel(
    const unsigned short* __restrict__ A,
    const unsigned short* __restrict__ DT,
    float* __restrict__ out,
    const int* __restrict__ perm, const int* __restrict__ tile_e,
    const int* __restrict__ tile_p, const int* __restrict__ offsets,
    const int* __restrict__ n_tiles)
{
  __shared__ short Al[BM * BK];   // 16KB
  __shared__ short Dl[128 * BK];  // 16KB  (32KB total)

  const int tid = threadIdx.x;
  const int wave = tid >> 6, lane = tid & 63;
  const int wm = wave >> 1, wn = wave & 1;

  int row0, row_end;
  const unsigned short* Dt;
  if constexpr (ROUTED) {
    if ((int)blockIdx.y >= *n_tiles) return;
    const int e = tile_e[blockIdx.y];
    row0 = tile_p[blockIdx.y];
    row_end = offsets[e + 1];
    Dt = DT + (size_t)e * H * IDIM;
  } else {
    row0 = blockIdx.y * BM; row_end = row0 + BM;
    Dt = DT;
  }
  const int n0 = blockIdx.x * 128;

  const unsigned short *asrc[4], *dsrc[4];
  int soff[4];
  #pragma unroll
  for (int i = 0; i < 4; ++i) {
    const int r = wave * 32 + i * 8 + (lane >> 3);
    int p = row0 + r;
    if (ROUTED && p >= row_end) p = row0;
    const int cb = ((lane & 7) * 16) ^ ((r & 7) << 4);
    asrc[i] = A  + (size_t)p * IDIM + (cb >> 1);        // sorted rows (routed)
    dsrc[i] = Dt + (size_t)(n0 + r) * IDIM + (cb >> 1);
    soff[i] = (wave * 32 + i * 8) * BK;
  }

  f32x4 acc[4][4] = {};

  #pragma unroll 1
  for (int kt = 0; kt < IDIM / BK; ++kt) {
    __syncthreads();
    #pragma unroll
    for (int i = 0; i < 4; ++i) gll16(asrc[i] + kt * BK, Al + soff[i]);
    #pragma unroll
    for (int i = 0; i < 4; ++i) gll16(dsrc[i] + kt * BK, Dl + soff[i]);
    __syncthreads();

    #pragma unroll
    for (int kk = 0; kk < 2; ++kk) {
      short8 af[4];
      #pragma unroll
      for (int m = 0; m < 4; ++m) {
        const int r = wm * 64 + m * 16 + (lane & 15);
        const int cb = (kk * 64 + ((lane >> 4) * 16)) ^ ((r & 7) << 4);
        af[m] = *(const short8*)((const char*)Al + r * 128 + cb);
      }
      #pragma unroll
      for (int nf = 0; nf < 4; ++nf) {
        const int n = wn * 64 + nf * 16 + (lane & 15);
        const int cb = (kk * 64 + ((lane >> 4) * 16)) ^ ((n & 7) << 4);
        short8 bd = *(const short8*)((const char*)Dl + n * 128 + cb);
        #pragma unroll
        for (int m = 0; m < 4; ++m) acc[m][nf] = mfma16(af[m], bd, acc[m][nf]);
      }
    }
  }

  #pragma unroll
  for (int m = 0; m < 4; ++m)
    #pragma unroll
    for (int nf = 0; nf < 4; ++nf) {
      const int col = n0 + wn * 64 + nf * 16 + (lane & 15);
      #pragma unroll
      for (int j = 0; j < 4; ++j) {
        const int row = row0 + wm * 64 + m * 16 + ((lane >> 4) * 4) + j;
        const float v = acc[m][nf][j];
        if constexpr (ROUTED) {
          if (row < row_end) {
            const int t = perm[row];
            out[(size_t)t * H + col] += v;     // shared pass wrote first
          }
        } else {
          out[(size_t)row * H + col] = v;
        }
      }
    }
}

// ---- launch --------------------------------------------------------------

extern "C" void kernel_launch(void* const* d_in, const int* in_sizes, int n_in,
                              void* d_out, int out_size, void* d_ws, size_t ws_size,
                              hipStream_t stream) {
  (void)in_sizes; (void)n_in; (void)out_size; (void)ws_size;
  const float* x      = (const float*)d_in[0];
  const float* gate_w = (const float*)d_in[1];
  const float* sgw    = (const float*)d_in[2];
  const float* suw    = (const float*)d_in[3];
  const float* sdw    = (const float*)d_in[4];
  const float* rgw    = (const float*)d_in[5];
  const float* ruw    = (const float*)d_in[6];
  const float* rdw    = (const float*)d_in[7];
  float* out = (float*)d_out;

  char* ws = (char*)d_ws;
  unsigned short* xbf    = (unsigned short*)(ws + 0);          // 16MB
  unsigned short* xsbf   = (unsigned short*)(ws + 16777216);   // 16MB
  unsigned short* act_sh = (unsigned short*)(ws + 33554432);   // 32MB
  int* perm      = (int*)(ws + 67108864);
  int* expert_id = (int*)(ws + 67141632);
  int* counts    = (int*)(ws + 67174400);
  int* offsets   = (int*)(ws + 67174528);
  int* cursor    = (int*)(ws + 67174784);
  int* tile_e    = (int*)(ws + 67174912);
  int* tile_p    = (int*)(ws + 67175424);
  int* n_tiles   = (int*)(ws + 67175936);
  // bf16 transposed weights + act_rt (uses ~516MB of ws)
  unsigned short* rgwT   = (unsigned short*)(ws + 68157440);   // 134MB
  unsigned short* ruwT   = (unsigned short*)(ws + 202375168);  // 134MB
  unsigned short* rdwT   = (unsigned short*)(ws + 336592896);  // 134MB
  unsigned short* sgwT   = (unsigned short*)(ws + 470810624);  // 4MB
  unsigned short* suwT   = (unsigned short*)(ws + 475004928);  // 4MB
  unsigned short* sdwT   = (unsigned short*)(ws + 479199232);  // 4MB
  unsigned short* act_rt = (unsigned short*)(ws + 483393536);  // 32MB

  hipMemsetAsync(counts, 0, NE * sizeof(int), stream);

  // routing (tiny, independent)
  router_kernel<<<TOK / 8, 256, 0, stream>>>(x, gate_w, xbf, xsbf, expert_id, counts);
  scan_kernel<<<1, 64, 0, stream>>>(counts, offsets, cursor, tile_e, tile_p, n_tiles);
  perm_kernel<<<TOK / 256, 256, 0, stream>>>(expert_id, cursor, perm);

  // gate+up weights: convert then consume in ONE merged launch
  tconv_kernel<<<dim3(H / 64, IDIM / 64, 1), 256, 0, stream>>>(sgw, sgwT, H, IDIM);
  tconv_kernel<<<dim3(H / 64, IDIM / 64, 1), 256, 0, stream>>>(suw, suwT, H, IDIM);
  tconv_kernel<<<dim3(H / 64, IDIM / 64, NE), 256, 0, stream>>>(rgw, rgwT, H, IDIM);
  tconv_kernel<<<dim3(H / 64, IDIM / 64, NE), 256, 0, stream>>>(ruw, ruwT, H, IDIM);
  gu_kernel<<<dim3(IDIM / 128, TOK / BM + MAX_TILES), 256, 0, stream>>>(
      xbf, xsbf, sgwT, suwT, rgwT, ruwT, act_sh, act_rt,
      perm, tile_e, tile_p, offsets, n_tiles);

  // down weights: convert (138MB ~ L3) then serial dn pair
  tconv_kernel<<<dim3(IDIM / 64, H / 64, 1), 256, 0, stream>>>(sdw, sdwT, IDIM, H);
  tconv_kernel<<<dim3(IDIM / 64, H / 64, NE), 256, 0, stream>>>(rdw, rdwT, IDIM, H);
  dn_kernel<false><<<dim3(H / 128, TOK / BM), 256, 0, stream>>>(
      act_sh, sdwT, out, perm, tile_e, tile_p, offsets, n_tiles);
  dn_kernel<true><<<dim3(H / 128, MAX_TILES), 256, 0, stream>>>(
      act_rt, rdwT, out, perm, tile_e, tile_p, offsets, n_tiles);
}

// Round 21
// 623.998 us; speedup vs baseline: 1.0444x; 1.0444x over previous
//
#include <hip/hip_runtime.h>
#include <stdint.h>
#include <stddef.h>

#define TOK 8192
#define H 1024
#define IDIM 2048
#define NE 32
#define BM 128
#define BK 64
#define MAX_TILES 96
#define GUTILES (TOK / BM + MAX_TILES)       // 160 gemm tiles in y
#define DNCONV_TILES 16896                    // (IDIM/64)*(H/64)*(NE+1)

typedef __attribute__((ext_vector_type(8))) short short8;
typedef __attribute__((ext_vector_type(4))) float f32x4;
typedef __attribute__((ext_vector_type(4))) float float4v;
typedef __attribute__((ext_vector_type(4))) unsigned int uint4v;

// ---- helpers -------------------------------------------------------------

__device__ __forceinline__ unsigned short f2bf(float x) {   // RNE fp32->bf16
  unsigned u = __builtin_bit_cast(unsigned, x);
  u += 0x7fffu + ((u >> 16) & 1u);
  return (unsigned short)(u >> 16);
}

// HW packed convert: lo -> bits[15:0], hi -> bits[31:16], RNE.
__device__ __forceinline__ unsigned cvtpk(float lo, float hi) {
  unsigned r;
  asm("v_cvt_pk_bf16_f32 %0, %1, %2" : "=v"(r) : "v"(lo), "v"(hi));
  return r;
}

// async global->LDS, 16B per lane; LDS dest = wave-uniform base + lane*16
__device__ __forceinline__ void gll16(const void* g, void* l) {
  __builtin_amdgcn_global_load_lds(
      (const __attribute__((address_space(1))) unsigned int*)g,
      (__attribute__((address_space(3))) unsigned int*)l, 16, 0, 0);
}

__device__ __forceinline__ f32x4 mfma16(short8 a, short8 b, f32x4 c) {
  return __builtin_amdgcn_mfma_f32_16x16x32_bf16(a, b, c, 0, 0, 0);
}

// tconv tile body: 64x64 transpose+convert, [K][N] fp32 -> [N][K] bf16
__device__ __forceinline__ void tconv_tile(
    const float* __restrict__ src, unsigned short* __restrict__ dst,
    int K, int N, int k0, int n0, int tid, void* smem)
{
  float (*t)[65] = (float(*)[65])smem;     // 16.6KB
  {
    const int r = tid >> 4;
    const int c = (tid & 15) * 4;
    #pragma unroll
    for (int i = 0; i < 4; ++i) {
      float4v v = *(const float4v*)(src + (size_t)(k0 + r + i * 16) * N + (n0 + c));
      t[r + i * 16][c + 0] = v[0];
      t[r + i * 16][c + 1] = v[1];
      t[r + i * 16][c + 2] = v[2];
      t[r + i * 16][c + 3] = v[3];
    }
  }
  __syncthreads();
  {
    const int n = tid >> 2;
    const int kc = (tid & 3) * 16;
    uint4v o0, o1;
    #pragma unroll
    for (int q = 0; q < 4; ++q) {
      o0[q] = cvtpk(t[kc + 2 * q][n],     t[kc + 2 * q + 1][n]);
      o1[q] = cvtpk(t[kc + 8 + 2 * q][n], t[kc + 8 + 2 * q + 1][n]);
    }
    unsigned short* dp = dst + (size_t)(n0 + n) * K + (k0 + kc);
    *(uint4v*)dp = o0;
    *(uint4v*)(dp + 8) = o1;
  }
}

// ---- 0) standalone weight transpose+convert ------------------------------

__global__ __launch_bounds__(256) void tconv_kernel(
    const float* __restrict__ src0, unsigned short* __restrict__ dst0,
    int K, int N)
{
  __shared__ float t[64][65];
  const size_t mat = (size_t)K * N;
  tconv_tile(src0 + (size_t)blockIdx.z * mat, dst0 + (size_t)blockIdx.z * mat,
             K, N, blockIdx.x * 64, blockIdx.y * 64, threadIdx.x, t);
}

// ---- 1) router: logits, top-1, sigmoid, bf16 casts ----------------------

__global__ __launch_bounds__(256) void router_kernel(
    const float* __restrict__ x, const float* __restrict__ gw,
    unsigned short* __restrict__ xbf, unsigned short* __restrict__ xsbf,
    int* __restrict__ expert_id, int* __restrict__ counts)
{
  __shared__ float xl[8 * H];          // 8 token rows, 32KB
  __shared__ float plog[8][8][NE];     // [chunk][tok][e]
  __shared__ float sscore[8];
  const int tid = threadIdx.x;
  const long t0 = (long)blockIdx.x * 8;

  const float4v* src = (const float4v*)(x + t0 * H);
  float4v* dst = (float4v*)xl;
  #pragma unroll
  for (int i = 0; i < 8; ++i) dst[tid + i * 256] = src[tid + i * 256];
  __syncthreads();

  {
    const int e = tid & 31, c = tid >> 5;
    float acc[8] = {0, 0, 0, 0, 0, 0, 0, 0};
    const float* gp = gw + (c * 128) * NE + e;
    for (int h = 0; h < 128; ++h) {
      float g = gp[h * NE];
      const float* xr = xl + (c * 128 + h);
      #pragma unroll
      for (int tk = 0; tk < 8; ++tk) acc[tk] += xr[tk * H] * g;
    }
    #pragma unroll
    for (int tk = 0; tk < 8; ++tk) plog[c][tk][e] = acc[tk];
  }
  __syncthreads();
  {
    const int e = tid & 31, tok = tid >> 5;
    float lg = 0.f;
    #pragma unroll
    for (int c = 0; c < 8; ++c) lg += plog[c][tok][e];
    float m = lg; int be = e;
    #pragma unroll
    for (int mask = 16; mask >= 1; mask >>= 1) {   // reduce within 32-lane group
      float om = __shfl_xor(m, mask);
      int   oe = __shfl_xor(be, mask);
      if (om > m || (om == m && oe < be)) { m = om; be = oe; }  // first-index tie
    }
    if (e == 0) {
      sscore[tok] = 1.f / (1.f + __expf(-m));
      expert_id[t0 + tok] = be;
      atomicAdd(&counts[be], 1);
    }
  }
  __syncthreads();
  {
    const float sc = sscore[tid >> 5];
    const int base = (tid >> 5) * H + (tid & 31) * 32;
    #pragma unroll
    for (int i = 0; i < 4; ++i) {
      uint4v vx, vs;
      #pragma unroll
      for (int q = 0; q < 4; ++q) {
        const float a = xl[base + i * 8 + 2 * q];
        const float b = xl[base + i * 8 + 2 * q + 1];
        vx[q] = cvtpk(a, b);
        vs[q] = cvtpk(a * sc, b * sc);
      }
      *(uint4v*)(xbf  + t0 * H + base + i * 8) = vx;
      *(uint4v*)(xsbf + t0 * H + base + i * 8) = vs;
    }
  }
}

// ---- 2) scan: offsets, cursors, tile table ------------------------------

__global__ void scan_kernel(const int* __restrict__ counts, int* __restrict__ offsets,
                            int* __restrict__ cursor, int* __restrict__ tile_e,
                            int* __restrict__ tile_p, int* __restrict__ n_tiles)
{
  if (threadIdx.x != 0) return;
  int off = 0, nt = 0;
  for (int e = 0; e < NE; ++e) {
    offsets[e] = off; cursor[e] = off;
    int cc = counts[e];
    for (int k = 0; k < cc; k += BM) { tile_e[nt] = e; tile_p[nt] = off + k; ++nt; }
    off += cc;
  }
  offsets[NE] = off;
  n_tiles[0] = nt;
}

// ---- 3) perm build -------------------------------------------------------

__global__ __launch_bounds__(256) void perm_kernel(
    const int* __restrict__ expert_id, int* __restrict__ cursor, int* __restrict__ perm)
{
  int t = blockIdx.x * 256 + threadIdx.x;
  int e = expert_id[t];
  int pos = atomicAdd(&cursor[e], 1);
  perm[pos] = t;
}

// ---- 4) MERGED gate+up GEMM + down-weight tconv (3 segments) -------------
// y < 64: shared gemm; 64 <= y < 160: routed gemm; y >= 160: tconv of the
// down weights (rdw/sdw -> bf16 T), soaking the ~5 TB/s of memory headroom
// gu leaves idle (gu is structure-bound at 29% MfmaUtil / 1.6 TB/s).
// Grid: x = n-panel (fast, 16), y = 160 + 1056.

__global__ __launch_bounds__(256, 2) void gu_kernel(
    const unsigned short* __restrict__ xbf,
    const unsigned short* __restrict__ xsbf,
    const unsigned short* __restrict__ SG, const unsigned short* __restrict__ SU,
    const unsigned short* __restrict__ RG, const unsigned short* __restrict__ RU,
    unsigned short* __restrict__ act_sh, unsigned short* __restrict__ act_rt,
    const float* __restrict__ SDW, const float* __restrict__ RDW,
    unsigned short* __restrict__ SDT, unsigned short* __restrict__ RDT,
    const int* __restrict__ perm, const int* __restrict__ tile_e,
    const int* __restrict__ tile_p, const int* __restrict__ offsets,
    const int* __restrict__ n_tiles)
{
  __shared__ char smem[49152];          // gu: A16+G16+U16 KB; tconv: 16.6KB

  const int tid = threadIdx.x;
  const int bidy = blockIdx.y;

  if (bidy >= GUTILES) {                // ---- tconv segment ----
    const int flat = (bidy - GUTILES) * (int)gridDim.x + (int)blockIdx.x;
    const float* src;
    unsigned short* dst;
    int rem;
    if (flat < 512 * NE) {              // routed down: e = flat>>9
      const int e = flat >> 9;
      rem = flat & 511;
      src = RDW + (size_t)e * IDIM * H;
      dst = RDT + (size_t)e * IDIM * H;
    } else {                            // shared down
      rem = flat - 512 * NE;
      src = SDW;
      dst = SDT;
    }
    tconv_tile(src, dst, IDIM, H, (rem >> 4) * 64, (rem & 15) * 64, tid, smem);
    return;
  }

  short* Al = (short*)smem;             // 16KB [row][k] swz byte^=(r&7)<<4
  short* Gl = Al + BM * BK;             // 16KB [n][k]
  short* Ul = Gl + 128 * BK;            // 16KB

  const int wave = tid >> 6, lane = tid & 63;
  const int wm = wave >> 1, wn = wave & 1;

  const bool routed = bidy >= (TOK / BM);
  int row0, row_end;
  const unsigned short *Gt, *Ut, *A;
  unsigned short* act;
  if (routed) {
    const int tx = bidy - TOK / BM;
    if (tx >= *n_tiles) return;
    const int e = tile_e[tx];
    row0 = tile_p[tx];
    row_end = offsets[e + 1];
    Gt = RG + (size_t)e * H * IDIM;
    Ut = RU + (size_t)e * H * IDIM;
    A = xsbf; act = act_rt;
  } else {
    row0 = bidy * BM; row_end = row0 + BM;
    Gt = SG; Ut = SU;
    A = xbf; act = act_sh;
  }
  const int n0 = blockIdx.x * 128;      // n-panel (fast dim)

  // staging descriptors: wave w stages rows [32w,32w+32) of each tile
  const unsigned short *asrc[4], *gsrc[4], *usrc[4];
  int soff[4];
  #pragma unroll
  for (int i = 0; i < 4; ++i) {
    const int r = wave * 32 + i * 8 + (lane >> 3);
    int p = row0 + r;
    if (routed && p >= row_end) p = row0;
    const int arow = routed ? perm[p] : p;
    const int cb = ((lane & 7) * 16) ^ ((r & 7) << 4);
    asrc[i] = A  + (size_t)arow * H + (cb >> 1);
    gsrc[i] = Gt + (size_t)(n0 + r) * H + (cb >> 1);
    usrc[i] = Ut + (size_t)(n0 + r) * H + (cb >> 1);
    soff[i] = (wave * 32 + i * 8) * BK;
  }

  f32x4 accg[4][4] = {};
  f32x4 accu[4][4] = {};

  #pragma unroll 1
  for (int kt = 0; kt < H / BK; ++kt) {
    __syncthreads();                    // prev compute done
    #pragma unroll
    for (int i = 0; i < 4; ++i) gll16(asrc[i] + kt * BK, Al + soff[i]);
    #pragma unroll
    for (int i = 0; i < 4; ++i) gll16(gsrc[i] + kt * BK, Gl + soff[i]);
    #pragma unroll
    for (int i = 0; i < 4; ++i) gll16(usrc[i] + kt * BK, Ul + soff[i]);
    __syncthreads();                    // vmcnt drained, tiles visible

    #pragma unroll
    for (int kk = 0; kk < 2; ++kk) {
      short8 af[4];
      #pragma unroll
      for (int m = 0; m < 4; ++m) {
        const int r = wm * 64 + m * 16 + (lane & 15);
        const int cb = (kk * 64 + ((lane >> 4) * 16)) ^ ((r & 7) << 4);
        af[m] = *(const short8*)((const char*)Al + r * 128 + cb);
      }
      #pragma unroll
      for (int nf = 0; nf < 4; ++nf) {
        const int n = wn * 64 + nf * 16 + (lane & 15);
        const int cb = (kk * 64 + ((lane >> 4) * 16)) ^ ((n & 7) << 4);
        short8 bg = *(const short8*)((const char*)Gl + n * 128 + cb);
        short8 bu = *(const short8*)((const char*)Ul + n * 128 + cb);
        #pragma unroll
        for (int m = 0; m < 4; ++m) {
          accg[m][nf] = mfma16(af[m], bg, accg[m][nf]);
          accu[m][nf] = mfma16(af[m], bu, accu[m][nf]);
        }
      }
    }
  }

  // epilogue: silu(g)*u -> bf16 act
  #pragma unroll
  for (int m = 0; m < 4; ++m)
    #pragma unroll
    for (int nf = 0; nf < 4; ++nf) {
      const int col = n0 + wn * 64 + nf * 16 + (lane & 15);
      #pragma unroll
      for (int j = 0; j < 4; ++j) {
        const int row = row0 + wm * 64 + m * 16 + ((lane >> 4) * 4) + j;
        if (routed && row >= row_end) continue;
        const float g = accg[m][nf][j];
        const float u = accu[m][nf][j];
        const float v = (g / (1.f + __expf(-g))) * u;
        act[(size_t)row * IDIM + col] = f2bf(v);
      }
    }
}

// ---- 5) down GEMM (serial pair, grid swapped): out = act @ Wd ------------

template<bool ROUTED>
__global__ __launch_bounds__(256, 4) void dn_kernel(
    const unsigned short* __restrict__ A,
    const unsigned short* __restrict__ DT,
    float* __restrict__ out,
    const int* __restrict__ perm, const int* __restrict__ tile_e,
    const int* __restrict__ tile_p, const int* __restrict__ offsets,
    const int* __restrict__ n_tiles)
{
  __shared__ short Al[BM * BK];   // 16KB
  __shared__ short Dl[128 * BK];  // 16KB  (32KB total)

  const int tid = threadIdx.x;
  const int wave = tid >> 6, lane = tid & 63;
  const int wm = wave >> 1, wn = wave & 1;

  int row0, row_end;
  const unsigned short* Dt;
  if constexpr (ROUTED) {
    if ((int)blockIdx.y >= *n_tiles) return;
    const int e = tile_e[blockIdx.y];
    row0 = tile_p[blockIdx.y];
    row_end = offsets[e + 1];
    Dt = DT + (size_t)e * H * IDIM;
  } else {
    row0 = blockIdx.y * BM; row_end = row0 + BM;
    Dt = DT;
  }
  const int n0 = blockIdx.x * 128;

  const unsigned short *asrc[4], *dsrc[4];
  int soff[4];
  #pragma unroll
  for (int i = 0; i < 4; ++i) {
    const int r = wave * 32 + i * 8 + (lane >> 3);
    int p = row0 + r;
    if (ROUTED && p >= row_end) p = row0;
    const int cb = ((lane & 7) * 16) ^ ((r & 7) << 4);
    asrc[i] = A  + (size_t)p * IDIM + (cb >> 1);        // sorted rows (routed)
    dsrc[i] = Dt + (size_t)(n0 + r) * IDIM + (cb >> 1);
    soff[i] = (wave * 32 + i * 8) * BK;
  }

  f32x4 acc[4][4] = {};

  #pragma unroll 1
  for (int kt = 0; kt < IDIM / BK; ++kt) {
    __syncthreads();
    #pragma unroll
    for (int i = 0; i < 4; ++i) gll16(asrc[i] + kt * BK, Al + soff[i]);
    #pragma unroll
    for (int i = 0; i < 4; ++i) gll16(dsrc[i] + kt * BK, Dl + soff[i]);
    __syncthreads();

    #pragma unroll
    for (int kk = 0; kk < 2; ++kk) {
      short8 af[4];
      #pragma unroll
      for (int m = 0; m < 4; ++m) {
        const int r = wm * 64 + m * 16 + (lane & 15);
        const int cb = (kk * 64 + ((lane >> 4) * 16)) ^ ((r & 7) << 4);
        af[m] = *(const short8*)((const char*)Al + r * 128 + cb);
      }
      #pragma unroll
      for (int nf = 0; nf < 4; ++nf) {
        const int n = wn * 64 + nf * 16 + (lane & 15);
        const int cb = (kk * 64 + ((lane >> 4) * 16)) ^ ((n & 7) << 4);
        short8 bd = *(const short8*)((const char*)Dl + n * 128 + cb);
        #pragma unroll
        for (int m = 0; m < 4; ++m) acc[m][nf] = mfma16(af[m], bd, acc[m][nf]);
      }
    }
  }

  #pragma unroll
  for (int m = 0; m < 4; ++m)
    #pragma unroll
    for (int nf = 0; nf < 4; ++nf) {
      const int col = n0 + wn * 64 + nf * 16 + (lane & 15);
      #pragma unroll
      for (int j = 0; j < 4; ++j) {
        const int row = row0 + wm * 64 + m * 16 + ((lane >> 4) * 4) + j;
        const float v = acc[m][nf][j];
        if constexpr (ROUTED) {
          if (row < row_end) {
            const int t = perm[row];
            out[(size_t)t * H + col] += v;     // shared pass wrote first
          }
        } else {
          out[(size_t)row * H + col] = v;
        }
      }
    }
}

// ---- launch --------------------------------------------------------------

extern "C" void kernel_launch(void* const* d_in, const int* in_sizes, int n_in,
                              void* d_out, int out_size, void* d_ws, size_t ws_size,
                              hipStream_t stream) {
  (void)in_sizes; (void)n_in; (void)out_size; (void)ws_size;
  const float* x      = (const float*)d_in[0];
  const float* gate_w = (const float*)d_in[1];
  const float* sgw    = (const float*)d_in[2];
  const float* suw    = (const float*)d_in[3];
  const float* sdw    = (const float*)d_in[4];
  const float* rgw    = (const float*)d_in[5];
  const float* ruw    = (const float*)d_in[6];
  const float* rdw    = (const float*)d_in[7];
  float* out = (float*)d_out;

  char* ws = (char*)d_ws;
  unsigned short* xbf    = (unsigned short*)(ws + 0);          // 16MB
  unsigned short* xsbf   = (unsigned short*)(ws + 16777216);   // 16MB
  unsigned short* act_sh = (unsigned short*)(ws + 33554432);   // 32MB
  int* perm      = (int*)(ws + 67108864);
  int* expert_id = (int*)(ws + 67141632);
  int* counts    = (int*)(ws + 67174400);
  int* offsets   = (int*)(ws + 67174528);
  int* cursor    = (int*)(ws + 67174784);
  int* tile_e    = (int*)(ws + 67174912);
  int* tile_p    = (int*)(ws + 67175424);
  int* n_tiles   = (int*)(ws + 67175936);
  // bf16 transposed weights + act_rt (uses ~516MB of ws)
  unsigned short* rgwT   = (unsigned short*)(ws + 68157440);   // 134MB
  unsigned short* ruwT   = (unsigned short*)(ws + 202375168);  // 134MB
  unsigned short* rdwT   = (unsigned short*)(ws + 336592896);  // 134MB
  unsigned short* sgwT   = (unsigned short*)(ws + 470810624);  // 4MB
  unsigned short* suwT   = (unsigned short*)(ws + 475004928);  // 4MB
  unsigned short* sdwT   = (unsigned short*)(ws + 479199232);  // 4MB
  unsigned short* act_rt = (unsigned short*)(ws + 483393536);  // 32MB

  hipMemsetAsync(counts, 0, NE * sizeof(int), stream);

  // routing (tiny, independent)
  router_kernel<<<TOK / 8, 256, 0, stream>>>(x, gate_w, xbf, xsbf, expert_id, counts);
  scan_kernel<<<1, 64, 0, stream>>>(counts, offsets, cursor, tile_e, tile_p, n_tiles);
  perm_kernel<<<TOK / 256, 256, 0, stream>>>(expert_id, cursor, perm);

  // gate+up weights: convert; then ONE merged launch = gu gemm + dn-weight tconv
  tconv_kernel<<<dim3(H / 64, IDIM / 64, 1), 256, 0, stream>>>(sgw, sgwT, H, IDIM);
  tconv_kernel<<<dim3(H / 64, IDIM / 64, 1), 256, 0, stream>>>(suw, suwT, H, IDIM);
  tconv_kernel<<<dim3(H / 64, IDIM / 64, NE), 256, 0, stream>>>(rgw, rgwT, H, IDIM);
  tconv_kernel<<<dim3(H / 64, IDIM / 64, NE), 256, 0, stream>>>(ruw, ruwT, H, IDIM);
  gu_kernel<<<dim3(IDIM / 128, GUTILES + DNCONV_TILES / (IDIM / 128)), 256, 0, stream>>>(
      xbf, xsbf, sgwT, suwT, rgwT, ruwT, act_sh, act_rt,
      sdw, rdw, sdwT, rdwT,
      perm, tile_e, tile_p, offsets, n_tiles);

  // down gemms (weights already converted inside the merged launch)
  dn_kernel<false><<<dim3(H / 128, TOK / BM), 256, 0, stream>>>(
      act_sh, sdwT, out, perm, tile_e, tile_p, offsets, n_tiles);
  dn_kernel<true><<<dim3(H / 128, MAX_TILES), 256, 0, stream>>>(
      act_rt, rdwT, out, perm, tile_e, tile_p, offsets, n_tiles);
}

// Round 22
// 596.015 us; speedup vs baseline: 1.0935x; 1.0470x over previous
//
#include <hip/hip_runtime.h>
#include <stdint.h>
#include <stddef.h>

#define TOK 8192
#define H 1024
#define IDIM 2048
#define NE 32
#define BM 128
#define BK 64
#define MAX_TILES 96
#define GUTILES (TOK / BM + MAX_TILES)       // 160 gemm tiles in y
#define DNCONV_TILES 16896                    // (IDIM/64)*(H/64)*(NE+1)
#define RT_BLOCKS (TOK / 8)                   // 1024 router blocks
#define GUCONV_TILES 33792                    // 512*(NE*2+2) gate/up tconv tiles

typedef __attribute__((ext_vector_type(8))) short short8;
typedef __attribute__((ext_vector_type(4))) float f32x4;
typedef __attribute__((ext_vector_type(4))) float float4v;
typedef __attribute__((ext_vector_type(4))) unsigned int uint4v;

// ---- helpers -------------------------------------------------------------

__device__ __forceinline__ unsigned short f2bf(float x) {   // RNE fp32->bf16
  unsigned u = __builtin_bit_cast(unsigned, x);
  u += 0x7fffu + ((u >> 16) & 1u);
  return (unsigned short)(u >> 16);
}

// HW packed convert: lo -> bits[15:0], hi -> bits[31:16], RNE.
__device__ __forceinline__ unsigned cvtpk(float lo, float hi) {
  unsigned r;
  asm("v_cvt_pk_bf16_f32 %0, %1, %2" : "=v"(r) : "v"(lo), "v"(hi));
  return r;
}

// async global->LDS, 16B per lane; LDS dest = wave-uniform base + lane*16
__device__ __forceinline__ void gll16(const void* g, void* l) {
  __builtin_amdgcn_global_load_lds(
      (const __attribute__((address_space(1))) unsigned int*)g,
      (__attribute__((address_space(3))) unsigned int*)l, 16, 0, 0);
}

__device__ __forceinline__ f32x4 mfma16(short8 a, short8 b, f32x4 c) {
  return __builtin_amdgcn_mfma_f32_16x16x32_bf16(a, b, c, 0, 0, 0);
}

// tconv tile body: 64x64 transpose+convert, [K][N] fp32 -> [N][K] bf16
__device__ __forceinline__ void tconv_tile(
    const float* __restrict__ src, unsigned short* __restrict__ dst,
    int K, int N, int k0, int n0, int tid, void* smem)
{
  float (*t)[65] = (float(*)[65])smem;     // 16.6KB
  {
    const int r = tid >> 4;
    const int c = (tid & 15) * 4;
    #pragma unroll
    for (int i = 0; i < 4; ++i) {
      float4v v = *(const float4v*)(src + (size_t)(k0 + r + i * 16) * N + (n0 + c));
      t[r + i * 16][c + 0] = v[0];
      t[r + i * 16][c + 1] = v[1];
      t[r + i * 16][c + 2] = v[2];
      t[r + i * 16][c + 3] = v[3];
    }
  }
  __syncthreads();
  {
    const int n = tid >> 2;
    const int kc = (tid & 3) * 16;
    uint4v o0, o1;
    #pragma unroll
    for (int q = 0; q < 4; ++q) {
      o0[q] = cvtpk(t[kc + 2 * q][n],     t[kc + 2 * q + 1][n]);
      o1[q] = cvtpk(t[kc + 8 + 2 * q][n], t[kc + 8 + 2 * q + 1][n]);
    }
    unsigned short* dp = dst + (size_t)(n0 + n) * K + (k0 + kc);
    *(uint4v*)dp = o0;
    *(uint4v*)(dp + 8) = o1;
  }
}

// ---- 1) MERGED router + gate/up-weight tconv -----------------------------
// blocks [0,1024): router (logits/top1/sigmoid/bf16 casts);
// blocks [1024,..): tconv tiles of rgw|ruw|sgw|suw (router's ~15us hides
// under the BW-bound conversion).

__global__ __launch_bounds__(256) void router_tconv_kernel(
    const float* __restrict__ x, const float* __restrict__ gw,
    unsigned short* __restrict__ xbf, unsigned short* __restrict__ xsbf,
    int* __restrict__ expert_id, int* __restrict__ counts,
    const float* __restrict__ sgw, const float* __restrict__ suw,
    const float* __restrict__ rgw, const float* __restrict__ ruw,
    unsigned short* __restrict__ sgwT, unsigned short* __restrict__ suwT,
    unsigned short* __restrict__ rgwT, unsigned short* __restrict__ ruwT)
{
  __shared__ char smem[41088];         // router: xl32K+plog8K+sc; tconv: 16.6K
  const int tid = threadIdx.x;
  const int b = blockIdx.x;

  if (b >= RT_BLOCKS) {                // ---- tconv segment ----
    const int flat = b - RT_BLOCKS;
    const float* src;
    unsigned short* dst;
    int rem;
    if (flat < 512 * NE) {                       // rgw
      const int e = flat >> 9; rem = flat & 511;
      src = rgw + (size_t)e * H * IDIM; dst = rgwT + (size_t)e * H * IDIM;
    } else if (flat < 1024 * NE) {               // ruw
      const int e = (flat - 512 * NE) >> 9; rem = flat & 511;
      src = ruw + (size_t)e * H * IDIM; dst = ruwT + (size_t)e * H * IDIM;
    } else if (flat < 1024 * NE + 512) {         // sgw
      rem = flat - 1024 * NE;
      src = sgw; dst = sgwT;
    } else {                                     // suw
      rem = flat - 1024 * NE - 512;
      src = suw; dst = suwT;
    }
    tconv_tile(src, dst, H, IDIM, (rem >> 5) * 64, (rem & 31) * 64, tid, smem);
    return;
  }

  // ---- router segment ----
  float* xl = (float*)smem;                       // 8*H floats
  float (*plog)[8][NE] = (float(*)[8][NE])(smem + 32768);
  float* sscore = (float*)(smem + 40960);
  const long t0 = (long)b * 8;

  const float4v* src = (const float4v*)(x + t0 * H);
  float4v* dst = (float4v*)xl;
  #pragma unroll
  for (int i = 0; i < 8; ++i) dst[tid + i * 256] = src[tid + i * 256];
  __syncthreads();

  {
    const int e = tid & 31, c = tid >> 5;
    float acc[8] = {0, 0, 0, 0, 0, 0, 0, 0};
    const float* gp = gw + (c * 128) * NE + e;
    for (int h = 0; h < 128; ++h) {
      float g = gp[h * NE];
      const float* xr = xl + (c * 128 + h);
      #pragma unroll
      for (int tk = 0; tk < 8; ++tk) acc[tk] += xr[tk * H] * g;
    }
    #pragma unroll
    for (int tk = 0; tk < 8; ++tk) plog[c][tk][e] = acc[tk];
  }
  __syncthreads();
  {
    const int e = tid & 31, tok = tid >> 5;
    float lg = 0.f;
    #pragma unroll
    for (int c = 0; c < 8; ++c) lg += plog[c][tok][e];
    float m = lg; int be = e;
    #pragma unroll
    for (int mask = 16; mask >= 1; mask >>= 1) {   // reduce within 32-lane group
      float om = __shfl_xor(m, mask);
      int   oe = __shfl_xor(be, mask);
      if (om > m || (om == m && oe < be)) { m = om; be = oe; }  // first-index tie
    }
    if (e == 0) {
      sscore[tok] = 1.f / (1.f + __expf(-m));
      expert_id[t0 + tok] = be;
      atomicAdd(&counts[be], 1);
    }
  }
  __syncthreads();
  {
    const float sc = sscore[tid >> 5];
    const int base = (tid >> 5) * H + (tid & 31) * 32;
    #pragma unroll
    for (int i = 0; i < 4; ++i) {
      uint4v vx, vs;
      #pragma unroll
      for (int q = 0; q < 4; ++q) {
        const float a = xl[base + i * 8 + 2 * q];
        const float bq = xl[base + i * 8 + 2 * q + 1];
        vx[q] = cvtpk(a, bq);
        vs[q] = cvtpk(a * sc, bq * sc);
      }
      *(uint4v*)(xbf  + t0 * H + base + i * 8) = vx;
      *(uint4v*)(xsbf + t0 * H + base + i * 8) = vs;
    }
  }
}

// ---- 2) scan: offsets, cursors, tile table ------------------------------

__global__ void scan_kernel(const int* __restrict__ counts, int* __restrict__ offsets,
                            int* __restrict__ cursor, int* __restrict__ tile_e,
                            int* __restrict__ tile_p, int* __restrict__ n_tiles)
{
  if (threadIdx.x != 0) return;
  int off = 0, nt = 0;
  for (int e = 0; e < NE; ++e) {
    offsets[e] = off; cursor[e] = off;
    int cc = counts[e];
    for (int k = 0; k < cc; k += BM) { tile_e[nt] = e; tile_p[nt] = off + k; ++nt; }
    off += cc;
  }
  offsets[NE] = off;
  n_tiles[0] = nt;
}

// ---- 3) perm build -------------------------------------------------------

__global__ __launch_bounds__(256) void perm_kernel(
    const int* __restrict__ expert_id, int* __restrict__ cursor, int* __restrict__ perm)
{
  int t = blockIdx.x * 256 + threadIdx.x;
  int e = expert_id[t];
  int pos = atomicAdd(&cursor[e], 1);
  perm[pos] = t;
}

// ---- 4) MERGED gate+up GEMM + down-weight tconv (r21-proven) -------------

__global__ __launch_bounds__(256, 2) void gu_kernel(
    const unsigned short* __restrict__ xbf,
    const unsigned short* __restrict__ xsbf,
    const unsigned short* __restrict__ SG, const unsigned short* __restrict__ SU,
    const unsigned short* __restrict__ RG, const unsigned short* __restrict__ RU,
    unsigned short* __restrict__ act_sh, unsigned short* __restrict__ act_rt,
    const float* __restrict__ SDW, const float* __restrict__ RDW,
    unsigned short* __restrict__ SDT, unsigned short* __restrict__ RDT,
    const int* __restrict__ perm, const int* __restrict__ tile_e,
    const int* __restrict__ tile_p, const int* __restrict__ offsets,
    const int* __restrict__ n_tiles)
{
  __shared__ char smem[49152];          // gu: A16+G16+U16 KB; tconv: 16.6KB

  const int tid = threadIdx.x;
  const int bidy = blockIdx.y;

  if (bidy >= GUTILES) {                // ---- tconv segment (down weights) --
    const int flat = (bidy - GUTILES) * (int)gridDim.x + (int)blockIdx.x;
    const float* src;
    unsigned short* dst;
    int rem;
    if (flat < 512 * NE) {              // routed down: e = flat>>9
      const int e = flat >> 9;
      rem = flat & 511;
      src = RDW + (size_t)e * IDIM * H;
      dst = RDT + (size_t)e * IDIM * H;
    } else {                            // shared down
      rem = flat - 512 * NE;
      src = SDW;
      dst = SDT;
    }
    tconv_tile(src, dst, IDIM, H, (rem >> 4) * 64, (rem & 15) * 64, tid, smem);
    return;
  }

  short* Al = (short*)smem;             // 16KB [row][k] swz byte^=(r&7)<<4
  short* Gl = Al + BM * BK;             // 16KB [n][k]
  short* Ul = Gl + 128 * BK;            // 16KB

  const int wave = tid >> 6, lane = tid & 63;
  const int wm = wave >> 1, wn = wave & 1;

  const bool routed = bidy >= (TOK / BM);
  int row0, row_end;
  const unsigned short *Gt, *Ut, *A;
  unsigned short* act;
  if (routed) {
    const int tx = bidy - TOK / BM;
    if (tx >= *n_tiles) return;
    const int e = tile_e[tx];
    row0 = tile_p[tx];
    row_end = offsets[e + 1];
    Gt = RG + (size_t)e * H * IDIM;
    Ut = RU + (size_t)e * H * IDIM;
    A = xsbf; act = act_rt;
  } else {
    row0 = bidy * BM; row_end = row0 + BM;
    Gt = SG; Ut = SU;
    A = xbf; act = act_sh;
  }
  const int n0 = blockIdx.x * 128;      // n-panel (fast dim)

  // staging descriptors: wave w stages rows [32w,32w+32) of each tile
  const unsigned short *asrc[4], *gsrc[4], *usrc[4];
  int soff[4];
  #pragma unroll
  for (int i = 0; i < 4; ++i) {
    const int r = wave * 32 + i * 8 + (lane >> 3);
    int p = row0 + r;
    if (routed && p >= row_end) p = row0;
    const int arow = routed ? perm[p] : p;
    const int cb = ((lane & 7) * 16) ^ ((r & 7) << 4);
    asrc[i] = A  + (size_t)arow * H + (cb >> 1);
    gsrc[i] = Gt + (size_t)(n0 + r) * H + (cb >> 1);
    usrc[i] = Ut + (size_t)(n0 + r) * H + (cb >> 1);
    soff[i] = (wave * 32 + i * 8) * BK;
  }

  f32x4 accg[4][4] = {};
  f32x4 accu[4][4] = {};

  #pragma unroll 1
  for (int kt = 0; kt < H / BK; ++kt) {
    __syncthreads();                    // prev compute done
    #pragma unroll
    for (int i = 0; i < 4; ++i) gll16(asrc[i] + kt * BK, Al + soff[i]);
    #pragma unroll
    for (int i = 0; i < 4; ++i) gll16(gsrc[i] + kt * BK, Gl + soff[i]);
    #pragma unroll
    for (int i = 0; i < 4; ++i) gll16(usrc[i] + kt * BK, Ul + soff[i]);
    __syncthreads();                    // vmcnt drained, tiles visible

    #pragma unroll
    for (int kk = 0; kk < 2; ++kk) {
      short8 af[4];
      #pragma unroll
      for (int m = 0; m < 4; ++m) {
        const int r = wm * 64 + m * 16 + (lane & 15);
        const int cb = (kk * 64 + ((lane >> 4) * 16)) ^ ((r & 7) << 4);
        af[m] = *(const short8*)((const char*)Al + r * 128 + cb);
      }
      #pragma unroll
      for (int nf = 0; nf < 4; ++nf) {
        const int n = wn * 64 + nf * 16 + (lane & 15);
        const int cb = (kk * 64 + ((lane >> 4) * 16)) ^ ((n & 7) << 4);
        short8 bg = *(const short8*)((const char*)Gl + n * 128 + cb);
        short8 bu = *(const short8*)((const char*)Ul + n * 128 + cb);
        #pragma unroll
        for (int m = 0; m < 4; ++m) {
          accg[m][nf] = mfma16(af[m], bg, accg[m][nf]);
          accu[m][nf] = mfma16(af[m], bu, accu[m][nf]);
        }
      }
    }
  }

  // epilogue: silu(g)*u -> bf16 act
  #pragma unroll
  for (int m = 0; m < 4; ++m)
    #pragma unroll
    for (int nf = 0; nf < 4; ++nf) {
      const int col = n0 + wn * 64 + nf * 16 + (lane & 15);
      #pragma unroll
      for (int j = 0; j < 4; ++j) {
        const int row = row0 + wm * 64 + m * 16 + ((lane >> 4) * 4) + j;
        if (routed && row >= row_end) continue;
        const float g = accg[m][nf][j];
        const float u = accu[m][nf][j];
        const float v = (g / (1.f + __expf(-g))) * u;
        act[(size_t)row * IDIM + col] = f2bf(v);
      }
    }
}

// ---- 5) MERGED down GEMM (shared->out, routed->out_rt; both plain stores)
// Top-1 routing => routed scatter is BIJECTIVE (each token in exactly one
// expert) => no accumulation, no ordering. Combine kernel adds the halves.

__global__ __launch_bounds__(256, 4) void dn_kernel(
    const unsigned short* __restrict__ act_sh,
    const unsigned short* __restrict__ act_rt,
    const unsigned short* __restrict__ SD, const unsigned short* __restrict__ RD,
    float* __restrict__ out, float* __restrict__ out_rt,
    const int* __restrict__ perm, const int* __restrict__ tile_e,
    const int* __restrict__ tile_p, const int* __restrict__ offsets,
    const int* __restrict__ n_tiles)
{
  __shared__ short Al[BM * BK];   // 16KB
  __shared__ short Dl[128 * BK];  // 16KB  (32KB total)

  const int tid = threadIdx.x;
  const int wave = tid >> 6, lane = tid & 63;
  const int wm = wave >> 1, wn = wave & 1;

  const int bidy = blockIdx.y;
  const bool routed = bidy >= (TOK / BM);
  int row0, row_end;
  const unsigned short *Dt, *A;
  if (routed) {
    const int tx = bidy - TOK / BM;
    if (tx >= *n_tiles) return;
    const int e = tile_e[tx];
    row0 = tile_p[tx];
    row_end = offsets[e + 1];
    Dt = RD + (size_t)e * H * IDIM;
    A = act_rt;
  } else {
    row0 = bidy * BM; row_end = row0 + BM;
    Dt = SD;
    A = act_sh;
  }
  const int n0 = blockIdx.x * 128;

  const unsigned short *asrc[4], *dsrc[4];
  int soff[4];
  #pragma unroll
  for (int i = 0; i < 4; ++i) {
    const int r = wave * 32 + i * 8 + (lane >> 3);
    int p = row0 + r;
    if (routed && p >= row_end) p = row0;
    const int cb = ((lane & 7) * 16) ^ ((r & 7) << 4);
    asrc[i] = A  + (size_t)p * IDIM + (cb >> 1);        // sorted rows (routed)
    dsrc[i] = Dt + (size_t)(n0 + r) * IDIM + (cb >> 1);
    soff[i] = (wave * 32 + i * 8) * BK;
  }

  f32x4 acc[4][4] = {};

  #pragma unroll 1
  for (int kt = 0; kt < IDIM / BK; ++kt) {
    __syncthreads();
    #pragma unroll
    for (int i = 0; i < 4; ++i) gll16(asrc[i] + kt * BK, Al + soff[i]);
    #pragma unroll
    for (int i = 0; i < 4; ++i) gll16(dsrc[i] + kt * BK, Dl + soff[i]);
    __syncthreads();

    #pragma unroll
    for (int kk = 0; kk < 2; ++kk) {
      short8 af[4];
      #pragma unroll
      for (int m = 0; m < 4; ++m) {
        const int r = wm * 64 + m * 16 + (lane & 15);
        const int cb = (kk * 64 + ((lane >> 4) * 16)) ^ ((r & 7) << 4);
        af[m] = *(const short8*)((const char*)Al + r * 128 + cb);
      }
      #pragma unroll
      for (int nf = 0; nf < 4; ++nf) {
        const int n = wn * 64 + nf * 16 + (lane & 15);
        const int cb = (kk * 64 + ((lane >> 4) * 16)) ^ ((n & 7) << 4);
        short8 bd = *(const short8*)((const char*)Dl + n * 128 + cb);
        #pragma unroll
        for (int m = 0; m < 4; ++m) acc[m][nf] = mfma16(af[m], bd, acc[m][nf]);
      }
    }
  }

  #pragma unroll
  for (int m = 0; m < 4; ++m)
    #pragma unroll
    for (int nf = 0; nf < 4; ++nf) {
      const int col = n0 + wn * 64 + nf * 16 + (lane & 15);
      #pragma unroll
      for (int j = 0; j < 4; ++j) {
        const int row = row0 + wm * 64 + m * 16 + ((lane >> 4) * 4) + j;
        if (routed && row >= row_end) continue;
        const float v = acc[m][nf][j];
        if (routed) {
          const int t = perm[row];
          out_rt[(size_t)t * H + col] = v;   // bijective scatter, plain store
        } else {
          out[(size_t)row * H + col] = v;
        }
      }
    }
}

// ---- 6) combine: out += out_rt ------------------------------------------

__global__ __launch_bounds__(256) void combine_kernel(
    float* __restrict__ out, const float* __restrict__ out_rt)
{
  const size_t i = ((size_t)blockIdx.x * 256 + threadIdx.x) * 4;
  float4v a = *(float4v*)(out + i);
  float4v b = *(const float4v*)(out_rt + i);
  a[0] += b[0]; a[1] += b[1]; a[2] += b[2]; a[3] += b[3];
  *(float4v*)(out + i) = a;
}

// ---- launch --------------------------------------------------------------

extern "C" void kernel_launch(void* const* d_in, const int* in_sizes, int n_in,
                              void* d_out, int out_size, void* d_ws, size_t ws_size,
                              hipStream_t stream) {
  (void)in_sizes; (void)n_in; (void)out_size; (void)ws_size;
  const float* x      = (const float*)d_in[0];
  const float* gate_w = (const float*)d_in[1];
  const float* sgw    = (const float*)d_in[2];
  const float* suw    = (const float*)d_in[3];
  const float* sdw    = (const float*)d_in[4];
  const float* rgw    = (const float*)d_in[5];
  const float* ruw    = (const float*)d_in[6];
  const float* rdw    = (const float*)d_in[7];
  float* out = (float*)d_out;

  char* ws = (char*)d_ws;
  unsigned short* xbf    = (unsigned short*)(ws + 0);          // 16MB
  unsigned short* xsbf   = (unsigned short*)(ws + 16777216);   // 16MB
  unsigned short* act_sh = (unsigned short*)(ws + 33554432);   // 32MB
  int* perm      = (int*)(ws + 67108864);
  int* expert_id = (int*)(ws + 67141632);
  int* counts    = (int*)(ws + 67174400);
  int* offsets   = (int*)(ws + 67174528);
  int* cursor    = (int*)(ws + 67174784);
  int* tile_e    = (int*)(ws + 67174912);
  int* tile_p    = (int*)(ws + 67175424);
  int* n_tiles   = (int*)(ws + 67175936);
  unsigned short* rgwT   = (unsigned short*)(ws + 68157440);   // 134MB
  unsigned short* ruwT   = (unsigned short*)(ws + 202375168);  // 134MB
  unsigned short* rdwT   = (unsigned short*)(ws + 336592896);  // 134MB
  unsigned short* sgwT   = (unsigned short*)(ws + 470810624);  // 4MB
  unsigned short* suwT   = (unsigned short*)(ws + 475004928);  // 4MB
  unsigned short* sdwT   = (unsigned short*)(ws + 479199232);  // 4MB
  unsigned short* act_rt = (unsigned short*)(ws + 483393536);  // 32MB
  float*          out_rt = (float*)(ws + 516947968);           // 32MB

  hipMemsetAsync(counts, 0, NE * sizeof(int), stream);

  // merged router + gate/up-weight tconv
  router_tconv_kernel<<<RT_BLOCKS + GUCONV_TILES, 256, 0, stream>>>(
      x, gate_w, xbf, xsbf, expert_id, counts,
      sgw, suw, rgw, ruw, sgwT, suwT, rgwT, ruwT);
  scan_kernel<<<1, 64, 0, stream>>>(counts, offsets, cursor, tile_e, tile_p, n_tiles);
  perm_kernel<<<TOK / 256, 256, 0, stream>>>(expert_id, cursor, perm);

  // merged gu gemm + down-weight tconv
  gu_kernel<<<dim3(IDIM / 128, GUTILES + DNCONV_TILES / (IDIM / 128)), 256, 0, stream>>>(
      xbf, xsbf, sgwT, suwT, rgwT, ruwT, act_sh, act_rt,
      sdw, rdw, sdwT, rdwT,
      perm, tile_e, tile_p, offsets, n_tiles);

  // merged down gemms (plain stores, bijective routed scatter) + combine
  dn_kernel<<<dim3(H / 128, TOK / BM + MAX_TILES), 256, 0, stream>>>(
      act_sh, act_rt, sdwT, rdwT, out, out_rt,
      perm, tile_e, tile_p, offsets, n_tiles);
  combine_kernel<<<TOK * H / 1024, 256, 0, stream>>>(out, out_rt);
}